// Round 8
// baseline (3870.259 us; speedup 1.0000x reference)
//
#include <hip/hip_runtime.h>
#include <cstdint>
#include <cstddef>

typedef unsigned int u32;
typedef unsigned long long u64;

#define NBATCH 8192
#define SEQLEN 64
#define ZDIM   256
#define HDIM   64
#define NNEUR  128
#define EMID   160
#define DMID   96
#define TILE   32

__device__ __forceinline__ u32 rotl32(u32 v, int s){ return (v << s) | (v >> (32 - s)); }

// Threefry2x32, 20 rounds — exact JAX schedule.
__device__ __forceinline__ void tf2x32(u32 k0, u32 k1, u32 x0, u32 x1, u32& y0, u32& y1){
  u32 ks2 = k0 ^ k1 ^ 0x1BD11BDAu;
  x0 += k0; x1 += k1;
#define TF_R(r) { x0 += x1; x1 = rotl32(x1, (r)); x1 ^= x0; }
  TF_R(13) TF_R(15) TF_R(26) TF_R(6)
  x0 += k1;  x1 += ks2 + 1u;
  TF_R(17) TF_R(29) TF_R(16) TF_R(24)
  x0 += ks2; x1 += k0 + 2u;
  TF_R(13) TF_R(15) TF_R(26) TF_R(6)
  x0 += k0;  x1 += k1 + 3u;
  TF_R(17) TF_R(29) TF_R(16) TF_R(24)
  x0 += k1;  x1 += ks2 + 4u;
  TF_R(13) TF_R(15) TF_R(26) TF_R(6)
  x0 += ks2; x1 += k0 + 5u;
#undef TF_R
  y0 = x0; y1 = x1;
}

__device__ __forceinline__ float sigmf(float x){ return 1.0f / (1.0f + expf(-x)); }

__device__ __forceinline__ float dot4acc(float4 w, float4 v, float a){
  a = fmaf(w.x, v.x, a); a = fmaf(w.y, v.y, a);
  a = fmaf(w.z, v.z, a); a = fmaf(w.w, v.w, a);
  return a;
}

__global__ void __launch_bounds__(512, 2)
bar_decoder_kernel(const float* __restrict__ z,
                   const float* __restrict__ W_enc1, const float* __restrict__ b_enc1,
                   const float* __restrict__ W_enc2, const float* __restrict__ b_enc2,
                   const float* __restrict__ W_ih0,  const float* __restrict__ W_hh0,
                   const float* __restrict__ b_ih0,  const float* __restrict__ b_hh0,
                   const float* __restrict__ W_ih1,  const float* __restrict__ W_hh1,
                   const float* __restrict__ b_ih1,  const float* __restrict__ b_hh1,
                   const float* __restrict__ W_dec1, const float* __restrict__ b_dec1,
                   const float* __restrict__ W_dec2, const float* __restrict__ b_dec2,
                   float* __restrict__ out)   // f32: weights [0,2^26), samples at 2^26
{
  // LDS layout (bytes), total 49664:
  //   h0buf [32][64]  @0      (8192)
  //   h1buf [32][64]  @8192   (8192)
  //   keyw  [64][2]   @16384  (512)
  //   trans           @16896  (32768):
  //     gates [32][256] @16896          (phases A/B)
  //     d1    [32][100] @16896          (phase C)   — overlays gates
  //     lg    [32][128] @29696          (phase D/E) — overlays gates
  //     mid   [32][164] @16896          (encoder)
  //   encv  [32][68]  @0               (encoder, over h bufs)
  __shared__ __align__(16) char buf[49664];
  float* h0buf = (float*)buf;
  float* h1buf = (float*)(buf + 8192);
  u32*   keyw  = (u32*)  (buf + 16384);
  float* gates = (float*)(buf + 16896);
  float* d1    = (float*)(buf + 16896);
  float* lgb   = (float*)(buf + 29696);
  float* mid   = (float*)(buf + 16896);
  float* encv  = (float*)buf;

  const int t     = threadIdx.x;
  const int tile0 = blockIdx.x * TILE;
  const int r  = t & 255;   // LSTM gate row 0..255
  const int bh = t >> 8;    // batch half (16 batches each)
  const int j  = t & 63;    // combine unit
  const int cq = t >> 6;    // combine batch-quad 0..7
  const int dn = t & 127;   // dec row
  const int dq = t >> 7;    // dec batch group 0..3

  // ---------------- encoder: mid = relu(z @ Wenc1^T + b1) ----------------
  if (t < EMID) {
    float acc[TILE];
    float bb = b_enc1[t];
    #pragma unroll
    for (int b = 0; b < TILE; ++b) acc[b] = bb;
    const float4* wr = (const float4*)(W_enc1 + (size_t)t * ZDIM);
    #pragma unroll 2
    for (int k4 = 0; k4 < 64; ++k4){
      float4 w = wr[k4];
      for (int b = 0; b < TILE; ++b){
        float4 zv = *(const float4*)(z + (size_t)(tile0 + b) * ZDIM + k4 * 4);
        acc[b] = dot4acc(w, zv, acc[b]);
      }
    }
    #pragma unroll
    for (int b = 0; b < TILE; ++b) mid[b * 164 + t] = fmaxf(acc[b], 0.0f);
  }
  __syncthreads();

  // ---------------- enc = mid @ Wenc2^T + b2 -> encv ----------------
  if (t < HDIM) {
    float acc[TILE];
    float bb = b_enc2[t];
    #pragma unroll
    for (int b = 0; b < TILE; ++b) acc[b] = bb;
    const float4* wr = (const float4*)(W_enc2 + (size_t)t * EMID);
    #pragma unroll 2
    for (int k4 = 0; k4 < 40; ++k4){
      float4 w = wr[k4];
      for (int b = 0; b < TILE; ++b){
        float4 v = *(const float4*)(mid + b * 164 + k4 * 4);
        acc[b] = dot4acc(w, v, acc[b]);
      }
    }
    #pragma unroll
    for (int b = 0; b < TILE; ++b) encv[b * 68 + t] = acc[b];
  }
  __syncthreads();

  // ---------------- xg0 into registers: thread (r, bh), 16 batches ----------------
  float xg0r[16];
  {
    float bb = b_ih0[r] + b_hh0[r];
    #pragma unroll
    for (int i = 0; i < 16; ++i) xg0r[i] = bb;
    const float4* wr = (const float4*)(W_ih0 + (size_t)r * HDIM);
    #pragma unroll
    for (int k4 = 0; k4 < 16; ++k4){
      float4 w = wr[k4];
      #pragma unroll
      for (int i = 0; i < 16; ++i){
        float4 ev = *(const float4*)(encv + (bh * 16 + i) * 68 + k4 * 4);
        xg0r[i] = dot4acc(w, ev, xg0r[i]);
      }
    }
  }
  __syncthreads();   // encv dead; h bufs can be zeroed

  // ---------------- persistent register state ----------------
  float4 w0r[16], w1r[16], w2r[16];
  {
    const float4* p0 = (const float4*)(W_hh0 + (size_t)r * HDIM);
    const float4* p1 = (const float4*)(W_ih1 + (size_t)r * HDIM);
    const float4* p2 = (const float4*)(W_hh1 + (size_t)r * HDIM);
    #pragma unroll
    for (int k4 = 0; k4 < 16; ++k4){ w0r[k4] = p0[k4]; w1r[k4] = p1[k4]; w2r[k4] = p2[k4]; }
  }
  const float bias1r = b_ih1[r] + b_hh1[r];
  const float bd1 = (dn < DMID) ? b_dec1[dn] : 0.0f;
  const float bd2 = b_dec2[dn];

  if (t < SEQLEN) {
    u32 a0, a1;
    tf2x32(0u, 42u, 0u, (u32)t, a0, a1);   // partitionable split of key(42)
    keyw[2 * t] = a0; keyw[2 * t + 1] = a1;
  }
  for (int i = t; i < TILE * HDIM; i += 512){ h0buf[i] = 0.0f; h1buf[i] = 0.0f; }
  float c0r[4] = {0,0,0,0}, c1r[4] = {0,0,0,0};
  __syncthreads();

  for (int s = 0; s < SEQLEN; ++s){
    // ---------- A: layer0 gates = xg0 + h0_prev @ Whh0row ----------
    #pragma unroll
    for (int bq4 = 0; bq4 < 4; ++bq4){
      float a[4];
      #pragma unroll
      for (int bi = 0; bi < 4; ++bi) a[bi] = xg0r[bq4 * 4 + bi];
      #pragma unroll
      for (int k4 = 0; k4 < 16; ++k4){
        #pragma unroll
        for (int bi = 0; bi < 4; ++bi){
          float4 hv = *(const float4*)(h0buf + (bh * 16 + bq4 * 4 + bi) * 64 + k4 * 4);
          a[bi] = dot4acc(w0r[k4], hv, a[bi]);
        }
      }
      #pragma unroll
      for (int bi = 0; bi < 4; ++bi)
        gates[(bh * 16 + bq4 * 4 + bi) * 256 + r] = a[bi];
    }
    __syncthreads();   // 1

    // ---------- A-combine: c0/h0 update (thread (j, cq), 4 batches) ----------
    #pragma unroll
    for (int bi = 0; bi < 4; ++bi){
      int b = cq * 4 + bi;
      float ig = sigmf(gates[b * 256 + j]);
      float fg = sigmf(gates[b * 256 + 64 + j]);
      float gg = tanhf(gates[b * 256 + 128 + j]);
      float og = sigmf(gates[b * 256 + 192 + j]);
      float c  = fg * c0r[bi] + ig * gg;
      c0r[bi]  = c;
      h0buf[b * 64 + j] = og * tanhf(c);
    }
    __syncthreads();   // 2

    // ---------- B: layer1 gates = bias1 + h0 @ Wih1row + h1_prev @ Whh1row ----------
    #pragma unroll
    for (int bq4 = 0; bq4 < 4; ++bq4){
      float a[4];
      #pragma unroll
      for (int bi = 0; bi < 4; ++bi) a[bi] = bias1r;
      #pragma unroll
      for (int k4 = 0; k4 < 16; ++k4){
        #pragma unroll
        for (int bi = 0; bi < 4; ++bi){
          float4 hv = *(const float4*)(h0buf + (bh * 16 + bq4 * 4 + bi) * 64 + k4 * 4);
          a[bi] = dot4acc(w1r[k4], hv, a[bi]);
        }
      }
      #pragma unroll
      for (int k4 = 0; k4 < 16; ++k4){
        #pragma unroll
        for (int bi = 0; bi < 4; ++bi){
          float4 hv = *(const float4*)(h1buf + (bh * 16 + bq4 * 4 + bi) * 64 + k4 * 4);
          a[bi] = dot4acc(w2r[k4], hv, a[bi]);
        }
      }
      #pragma unroll
      for (int bi = 0; bi < 4; ++bi)
        gates[(bh * 16 + bq4 * 4 + bi) * 256 + r] = a[bi];
    }
    __syncthreads();   // 3

    // ---------- B-combine: c1/h1 update ----------
    #pragma unroll
    for (int bi = 0; bi < 4; ++bi){
      int b = cq * 4 + bi;
      float ig = sigmf(gates[b * 256 + j]);
      float fg = sigmf(gates[b * 256 + 64 + j]);
      float gg = tanhf(gates[b * 256 + 128 + j]);
      float og = sigmf(gates[b * 256 + 192 + j]);
      float c  = fg * c1r[bi] + ig * gg;
      c1r[bi]  = c;
      h1buf[b * 64 + j] = og * tanhf(c);
    }
    __syncthreads();   // 4

    // ---------- C: dec1 = relu(h1 @ Wdec1^T + b) (threads with dn<96; 8 batches) ----------
    if (dn < DMID){
      float a[8];
      #pragma unroll
      for (int q = 0; q < 8; ++q) a[q] = bd1;
      const float4* wr = (const float4*)(W_dec1 + (size_t)dn * HDIM);
      #pragma unroll
      for (int k4 = 0; k4 < 16; ++k4){
        float4 w = wr[k4];
        #pragma unroll
        for (int q = 0; q < 8; ++q){
          float4 hv = *(const float4*)(h1buf + (dq * 8 + q) * 64 + k4 * 4);
          a[q] = dot4acc(w, hv, a[q]);
        }
      }
      #pragma unroll
      for (int q = 0; q < 8; ++q) d1[(dq * 8 + q) * 100 + dn] = fmaxf(a[q], 0.0f);
    }
    __syncthreads();   // 5

    // ---------- D: dec2 logits (all threads; 8 batches) ----------
    {
      float a[8];
      #pragma unroll
      for (int q = 0; q < 8; ++q) a[q] = bd2;
      const float4* wr = (const float4*)(W_dec2 + (size_t)dn * DMID);
      #pragma unroll
      for (int k4 = 0; k4 < 24; ++k4){
        float4 w = wr[k4];
        #pragma unroll
        for (int q = 0; q < 8; ++q){
          float4 dv = *(const float4*)(d1 + (dq * 8 + q) * 100 + k4 * 4);
          a[q] = dot4acc(w, dv, a[q]);
        }
      }
      #pragma unroll
      for (int q = 0; q < 8; ++q) lgb[(dq * 8 + q) * 128 + dn] = a[q];
    }
    __syncthreads();   // 6

    // ---------- E: softmax + categorical sample (bl = t>>4, 16 lanes/batch) ----------
    {
      const int bl  = t >> 4;
      const int s16 = t & 15;
      const int bgl = tile0 + bl;

      float lv[8];
      {
        const float4* lrow = (const float4*)(lgb + bl * 128 + s16 * 8);
        float4 a = lrow[0], b = lrow[1];
        lv[0]=a.x; lv[1]=a.y; lv[2]=a.z; lv[3]=a.w;
        lv[4]=b.x; lv[5]=b.y; lv[6]=b.z; lv[7]=b.w;
      }
      float lmax = lv[0];
      #pragma unroll
      for (int i = 1; i < 8; ++i) lmax = fmaxf(lmax, lv[i]);
      #pragma unroll
      for (int m = 1; m < 16; m <<= 1) lmax = fmaxf(lmax, __shfl_xor(lmax, m));

      float esum = 0.0f; float ev[8];
      #pragma unroll
      for (int i = 0; i < 8; ++i){
        float e = expf(lv[i] - lmax);
        ev[i] = e; esum += e;
      }
      #pragma unroll
      for (int m = 1; m < 16; m <<= 1) esum += __shfl_xor(esum, m);
      float inv = 1.0f / esum;

      float4* wrow = (float4*)(out + (u64)bgl * (SEQLEN * NNEUR)
                                   + (u64)s * NNEUR + (u64)(s16 * 8));
      wrow[0] = make_float4(ev[0]*inv, ev[1]*inv, ev[2]*inv, ev[3]*inv);
      wrow[1] = make_float4(ev[4]*inv, ev[5]*inv, ev[6]*inv, ev[7]*inv);

      const u32 kk0 = keyw[2 * s];
      const u32 kk1 = keyw[2 * s + 1];
      float vmax = -3.402823466e38f; int vidx = 0;
      #pragma unroll
      for (int i = 0; i < 8; ++i){
        const int n = s16 * 8 + i;
        u32 y0, y1;
        tf2x32(kk0, kk1, 0u, (u32)(bgl * 128 + n), y0, y1);
        u32 bits = y0 ^ y1;
        float f  = __uint_as_float((bits >> 9) | 0x3f800000u) - 1.0f;
        float u  = f + 1.1754943508222875e-38f;   // f*(1-tiny)+tiny in f32
        u = fmaxf(u, 1.1754943508222875e-38f);
        float gmb = -logf(-logf(u));
        float val = gmb + lv[i];
        if (val > vmax){ vmax = val; vidx = n; }
      }
      #pragma unroll
      for (int m = 1; m < 16; m <<= 1){
        float ov = __shfl_xor(vmax, m);
        int   oi = __shfl_xor(vidx, m);
        if (ov > vmax || (ov == vmax && oi < vidx)){ vmax = ov; vidx = oi; }
      }
      if (s16 == 0)
        out[(u64)NBATCH * SEQLEN * NNEUR + (u64)bgl * SEQLEN + (u64)s] = (float)vidx;
    }
    __syncthreads();   // 7: protect lg (aliases gates) before next A-phase writes
  }
}

extern "C" void kernel_launch(void* const* d_in, const int* in_sizes, int n_in,
                              void* d_out, int out_size, void* d_ws, size_t ws_size,
                              hipStream_t stream) {
  (void)in_sizes; (void)n_in; (void)out_size; (void)d_ws; (void)ws_size;
  const float* z      = (const float*)d_in[0];
  // d_in[1]=score_tensor, d_in[2]=train: unused by the reference math
  const float* W_enc1 = (const float*)d_in[3];
  const float* b_enc1 = (const float*)d_in[4];
  const float* W_enc2 = (const float*)d_in[5];
  const float* b_enc2 = (const float*)d_in[6];
  const float* W_ih0  = (const float*)d_in[7];
  const float* W_hh0  = (const float*)d_in[8];
  const float* b_ih0  = (const float*)d_in[9];
  const float* b_hh0  = (const float*)d_in[10];
  const float* W_ih1  = (const float*)d_in[11];
  const float* W_hh1  = (const float*)d_in[12];
  const float* b_ih1  = (const float*)d_in[13];
  const float* b_hh1  = (const float*)d_in[14];
  const float* W_dec1 = (const float*)d_in[15];
  const float* b_dec1 = (const float*)d_in[16];
  const float* W_dec2 = (const float*)d_in[17];
  const float* b_dec2 = (const float*)d_in[18];

  float* out = (float*)d_out;

  dim3 grid(NBATCH / TILE);   // 256 blocks -> 1 per CU
  dim3 blk(512);
  hipLaunchKernelGGL(bar_decoder_kernel, grid, blk, 0, stream,
                     z, W_enc1, b_enc1, W_enc2, b_enc2,
                     W_ih0, W_hh0, b_ih0, b_hh0,
                     W_ih1, W_hh1, b_ih1, b_hh1,
                     W_dec1, b_dec1, W_dec2, b_dec2,
                     out);
}